// Round 11
// baseline (408.233 us; speedup 1.0000x reference)
//
#include <hip/hip_runtime.h>

#define NUM_GRAPHS 1024
#define D 256
#define TILE_ROWS 32              // 32 rows x 1KB = 32KB LDS tile

// ---------------------------------------------------------------------------
// init: zero the 1024 segment sums + 1024 counts each call.
// ---------------------------------------------------------------------------
__global__ void activs_init_kernel(float* __restrict__ sums, float* __restrict__ cnts) {
    int i = blockIdx.x * blockDim.x + threadIdx.x;
    if (i < NUM_GRAPHS) {
        sums[i] = 0.0f;
        cnts[i] = 0.0f;
    }
}

__device__ __forceinline__ float sq4(const float4 v) {
    return v.x * v.x + v.y * v.y + v.z * v.z + v.w * v.w;
}

// HBM -> LDS direct DMA, 16B per lane. LDS dest is WAVE-UNIFORM base
// (HW adds lane*16); global src is per-lane.
__device__ __forceinline__ void gload_lds16(const float* gsrc_lane, float* lds_base) {
    __builtin_amdgcn_global_load_lds(
        (const __attribute__((address_space(1))) void*)gsrc_lane,
        (__attribute__((address_space(3))) void*)lds_base,
        16, 0, 0);
}

// ---------------------------------------------------------------------------
// PHASE B: burst-phased streaming via LDS staging.
// Per block-tile (32 rows = 32KB): [8x global_load_lds per wave = 32KB read
// burst] -> barrier -> [ds_read_b128 + 32KB contiguous write burst; sq-sum
// partials reused from the store registers] -> reduce -> barrier.
// Coarsens each block's R/W alternation from ~1KB to 32KB and removes the
// VGPR round-trip on the load path. Wave w owns tile rows 8w..8w+7.
// ---------------------------------------------------------------------------
__global__ __launch_bounds__(256) void activs_stage_kernel(
        const float* __restrict__ x, float* __restrict__ out,
        float* __restrict__ norms, int N) {
    __shared__ float lds[TILE_ROWS * D];     // 32KB

    const int lane = threadIdx.x & 63;
    const int w = threadIdx.x >> 6;          // wave 0..3
    const int nTiles = N / TILE_ROWS;        // 1e6/32 = 31250 exact

    for (int t = blockIdx.x; t < nTiles; t += gridDim.x) {
        const int r0 = t * TILE_ROWS;        // first row of tile

        // ---- read burst: 8 x 1KB per wave, HBM -> LDS (async DMA) ----
        #pragma unroll
        for (int j = 0; j < 8; ++j) {
            const int rt = 8 * w + j;        // row within tile
            gload_lds16(x + (size_t)(r0 + rt) * D + lane * 4, lds + rt * D);
        }
        __syncthreads();                     // drains vmcnt: LDS tile ready

        // ---- write burst + norms: LDS -> regs -> HBM, sq-sums on the side --
        float s0, s1, s2, s3, s4, s5, s6, s7;
        {
            const int rt = 8 * w;
            float4 v;
            v = ((const float4*)(lds + (rt + 0) * D))[lane];
            ((float4*)(out + (size_t)(r0 + rt + 0) * D))[lane] = v; s0 = sq4(v);
            v = ((const float4*)(lds + (rt + 1) * D))[lane];
            ((float4*)(out + (size_t)(r0 + rt + 1) * D))[lane] = v; s1 = sq4(v);
            v = ((const float4*)(lds + (rt + 2) * D))[lane];
            ((float4*)(out + (size_t)(r0 + rt + 2) * D))[lane] = v; s2 = sq4(v);
            v = ((const float4*)(lds + (rt + 3) * D))[lane];
            ((float4*)(out + (size_t)(r0 + rt + 3) * D))[lane] = v; s3 = sq4(v);
            v = ((const float4*)(lds + (rt + 4) * D))[lane];
            ((float4*)(out + (size_t)(r0 + rt + 4) * D))[lane] = v; s4 = sq4(v);
            v = ((const float4*)(lds + (rt + 5) * D))[lane];
            ((float4*)(out + (size_t)(r0 + rt + 5) * D))[lane] = v; s5 = sq4(v);
            v = ((const float4*)(lds + (rt + 6) * D))[lane];
            ((float4*)(out + (size_t)(r0 + rt + 6) * D))[lane] = v; s6 = sq4(v);
            v = ((const float4*)(lds + (rt + 7) * D))[lane];
            ((float4*)(out + (size_t)(r0 + rt + 7) * D))[lane] = v; s7 = sq4(v);
        }

        // 8 full-wave butterflies (R10-proven free under the stream)
        #pragma unroll
        for (int m = 1; m <= 32; m <<= 1) {
            s0 += __shfl_xor(s0, m, 64);
            s1 += __shfl_xor(s1, m, 64);
            s2 += __shfl_xor(s2, m, 64);
            s3 += __shfl_xor(s3, m, 64);
            s4 += __shfl_xor(s4, m, 64);
            s5 += __shfl_xor(s5, m, 64);
            s6 += __shfl_xor(s6, m, 64);
            s7 += __shfl_xor(s7, m, 64);
        }
        float nv = s0;
        nv = (lane == 1) ? s1 : nv;
        nv = (lane == 2) ? s2 : nv;
        nv = (lane == 3) ? s3 : nv;
        nv = (lane == 4) ? s4 : nv;
        nv = (lane == 5) ? s5 : nv;
        nv = (lane == 6) ? s6 : nv;
        nv = (lane == 7) ? s7 : nv;
        if (lane < 8) norms[r0 + 8 * w + lane] = sqrtf(nv);

        __syncthreads();                     // protect LDS from next tile
    }

    // tail rows (N % 32; dead for N=1e6): block 0, wave 0
    if (blockIdx.x == 0 && w == 0) {
        for (int t = nTiles * TILE_ROWS; t < N; ++t) {
            const float4 v = ((const float4*)(x + (size_t)t * D))[lane];
            ((float4*)(out + (size_t)t * D))[lane] = v;
            float s = sq4(v);
            #pragma unroll
            for (int m = 32; m; m >>= 1) s += __shfl_xor(s, m, 64);
            if (lane == 0) norms[t] = sqrtf(s);
        }
    }
}

// ---------------------------------------------------------------------------
// PHASE C: segment reduce over norms (R8-proven). Each block owns 1024
// consecutive rows; each thread run-length-reduces 4 consecutive rows
// (batch sorted) into LDS bins; block flushes non-empty bins with global
// atomics (~2 pairs/block).
// ---------------------------------------------------------------------------
__global__ __launch_bounds__(256) void activs_segred_kernel(
        const float* __restrict__ norms, const int* __restrict__ batch,
        float* __restrict__ sums, float* __restrict__ cnts, int N) {
    __shared__ float lsum[NUM_GRAPHS];
    __shared__ float lcnt[NUM_GRAPHS];
    const int tid = threadIdx.x;

    for (int i = tid; i < NUM_GRAPHS; i += 256) {
        lsum[i] = 0.0f;
        lcnt[i] = 0.0f;
    }
    __syncthreads();

    const int base = blockIdx.x * 1024 + tid * 4;
    if (base < N) {
        const float4 nv = *(const float4*)(norms + base);
        const int4 bv = *(const int4*)(batch + base);
        const float n[4] = {nv.x, nv.y, nv.z, nv.w};
        const int b[4] = {bv.x, bv.y, bv.z, bv.w};
        int seg = b[0];
        float rs = n[0], rc = 1.0f;
        #pragma unroll
        for (int k = 1; k < 4; ++k) {
            if (b[k] == seg) { rs += n[k]; rc += 1.0f; }
            else {
                atomicAdd(&lsum[seg], rs);
                atomicAdd(&lcnt[seg], rc);
                seg = b[k]; rs = n[k]; rc = 1.0f;
            }
        }
        atomicAdd(&lsum[seg], rs);
        atomicAdd(&lcnt[seg], rc);
    }
    __syncthreads();

    for (int i = tid; i < NUM_GRAPHS; i += 256) {
        if (lcnt[i] != 0.0f) {
            atomicAdd(&sums[i], lsum[i]);
            atomicAdd(&cnts[i], lcnt[i]);
        }
    }
}

// ---------------------------------------------------------------------------
// FALLBACK (R6-style fused, full-row): used only if ws can't hold norms.
// ---------------------------------------------------------------------------
struct Rows8 {
    float4 v0, v1, v2, v3, v4, v5, v6, v7;
};

__device__ __forceinline__ void load8(Rows8& R, const float* __restrict__ x,
                                      int r, int lane) {
    R.v0 = ((const float4*)(x + (size_t)(r + 0) * D))[lane];
    R.v1 = ((const float4*)(x + (size_t)(r + 1) * D))[lane];
    R.v2 = ((const float4*)(x + (size_t)(r + 2) * D))[lane];
    R.v3 = ((const float4*)(x + (size_t)(r + 3) * D))[lane];
    R.v4 = ((const float4*)(x + (size_t)(r + 4) * D))[lane];
    R.v5 = ((const float4*)(x + (size_t)(r + 5) * D))[lane];
    R.v6 = ((const float4*)(x + (size_t)(r + 6) * D))[lane];
    R.v7 = ((const float4*)(x + (size_t)(r + 7) * D))[lane];
}

__device__ __forceinline__ void store8(const Rows8& R, float* __restrict__ out,
                                       int r, int lane) {
    ((float4*)(out + (size_t)(r + 0) * D))[lane] = R.v0;
    ((float4*)(out + (size_t)(r + 1) * D))[lane] = R.v1;
    ((float4*)(out + (size_t)(r + 2) * D))[lane] = R.v2;
    ((float4*)(out + (size_t)(r + 3) * D))[lane] = R.v3;
    ((float4*)(out + (size_t)(r + 4) * D))[lane] = R.v4;
    ((float4*)(out + (size_t)(r + 5) * D))[lane] = R.v5;
    ((float4*)(out + (size_t)(r + 6) * D))[lane] = R.v6;
    ((float4*)(out + (size_t)(r + 7) * D))[lane] = R.v7;
}

__global__ __launch_bounds__(256) void activs_fused_kernel(
        const float* __restrict__ x, const int* __restrict__ batch,
        float* __restrict__ out, float* __restrict__ sums,
        float* __restrict__ cnts, int N) {
    const int lane = threadIdx.x & 63;
    const int waveId = (blockIdx.x * blockDim.x + threadIdx.x) >> 6;
    const int totalWaves = (gridDim.x * blockDim.x) >> 6;
    const int stride = totalWaves * 8;
    const int Nq = N & ~7;

    int r = waveId * 8;
    if (r < Nq) {
        Rows8 cur;
        load8(cur, x, r, lane);
        int4 w0 = ((const int4*)(batch + r))[0];
        int4 w1 = ((const int4*)(batch + r))[1];

        while (true) {
            const int rn = r + stride;
            const bool more = (rn < Nq);
            Rows8 nxt;
            int4 nw0, nw1;
            if (more) {
                load8(nxt, x, rn, lane);
                nw0 = ((const int4*)(batch + rn))[0];
                nw1 = ((const int4*)(batch + rn))[1];
            }
            store8(cur, out, r, lane);

            float s0 = sq4(cur.v0), s1 = sq4(cur.v1);
            float s2 = sq4(cur.v2), s3 = sq4(cur.v3);
            float s4 = sq4(cur.v4), s5 = sq4(cur.v5);
            float s6 = sq4(cur.v6), s7 = sq4(cur.v7);
            #pragma unroll
            for (int m = 1; m <= 32; m <<= 1) {
                s0 += __shfl_xor(s0, m, 64);
                s1 += __shfl_xor(s1, m, 64);
                s2 += __shfl_xor(s2, m, 64);
                s3 += __shfl_xor(s3, m, 64);
                s4 += __shfl_xor(s4, m, 64);
                s5 += __shfl_xor(s5, m, 64);
                s6 += __shfl_xor(s6, m, 64);
                s7 += __shfl_xor(s7, m, 64);
            }

            if (lane == 0) {
                const float n[8] = {sqrtf(s0), sqrtf(s1), sqrtf(s2), sqrtf(s3),
                                    sqrtf(s4), sqrtf(s5), sqrtf(s6), sqrtf(s7)};
                const int b[8] = {w0.x, w0.y, w0.z, w0.w, w1.x, w1.y, w1.z, w1.w};
                int seg = b[0];
                float rs = n[0], rc = 1.0f;
                #pragma unroll
                for (int k = 1; k < 8; ++k) {
                    if (b[k] == seg) { rs += n[k]; rc += 1.0f; }
                    else {
                        atomicAdd(&sums[seg], rs);
                        atomicAdd(&cnts[seg], rc);
                        seg = b[k]; rs = n[k]; rc = 1.0f;
                    }
                }
                atomicAdd(&sums[seg], rs);
                atomicAdd(&cnts[seg], rc);
            }

            if (!more) break;
            cur = nxt; w0 = nw0; w1 = nw1; r = rn;
        }
    }
    if (waveId == 0) {
        for (int t = Nq; t < N; ++t) {
            const float4 v = ((const float4*)(x + (size_t)t * D))[lane];
            ((float4*)(out + (size_t)t * D))[lane] = v;
            float s = sq4(v);
            #pragma unroll
            for (int m = 32; m; m >>= 1) s += __shfl_xor(s, m, 64);
            if (lane == 0) {
                atomicAdd(&sums[batch[t]], sqrtf(s));
                atomicAdd(&cnts[batch[t]], 1.0f);
            }
        }
    }
}

// ---------------------------------------------------------------------------
// finalize: per_graph = sum/count; mask i < bmax; mean / (bmax + 1).
// ---------------------------------------------------------------------------
__global__ __launch_bounds__(1024) void activs_finalize_kernel(
        const float* __restrict__ sums, const float* __restrict__ cnts,
        const int* __restrict__ batch, int N, float* __restrict__ out_scalar) {
    __shared__ float red[16];
    const int i = threadIdx.x;
    const int lane = i & 63;
    const int w = i >> 6;

    const float bmax = (float)batch[N - 1];

    float c = cnts[i];
    float pg = (c > 0.0f) ? (sums[i] / c) : 0.0f;
    float val = (((float)i) < bmax) ? pg : 0.0f;

    #pragma unroll
    for (int m = 32; m; m >>= 1) val += __shfl_xor(val, m, 64);
    if (lane == 0) red[w] = val;
    __syncthreads();

    if (w == 0) {
        float v = (lane < 16) ? red[lane] : 0.0f;
        #pragma unroll
        for (int m = 8; m; m >>= 1) v += __shfl_xor(v, m, 64);
        if (lane == 0) out_scalar[0] = v / (bmax + 1.0f);
    }
}

// ---------------------------------------------------------------------------
extern "C" void kernel_launch(void* const* d_in, const int* in_sizes, int n_in,
                              void* d_out, int out_size, void* d_ws, size_t ws_size,
                              hipStream_t stream) {
    const float* x = (const float*)d_in[0];
    const int* batch = (const int*)d_in[1];
    float* out = (float*)d_out;

    const int N = in_sizes[1];                 // 1,000,000 rows (D = 256)

    const size_t need_norm = ((size_t)N + 2 * NUM_GRAPHS) * sizeof(float);

    if (ws_size >= need_norm) {
        float* norms = (float*)d_ws;           // [N]
        float* sums = norms + N;               // [1024]
        float* cnts = sums + NUM_GRAPHS;       // [1024]

        hipLaunchKernelGGL(activs_init_kernel, dim3(4), dim3(256), 0, stream, sums, cnts);
        hipLaunchKernelGGL(activs_stage_kernel, dim3(2048), dim3(256), 0, stream,
                           x, out, norms, N);
        hipLaunchKernelGGL(activs_segred_kernel, dim3((N + 1023) / 1024), dim3(256),
                           0, stream, norms, batch, sums, cnts, N);
        hipLaunchKernelGGL(activs_finalize_kernel, dim3(1), dim3(1024), 0, stream,
                           sums, cnts, batch, N, out + (size_t)N * D);
    } else {
        float* sums = (float*)d_ws;            // [1024]
        float* cnts = sums + NUM_GRAPHS;       // [1024]

        hipLaunchKernelGGL(activs_init_kernel, dim3(4), dim3(256), 0, stream, sums, cnts);
        hipLaunchKernelGGL(activs_fused_kernel, dim3(2048), dim3(256), 0, stream,
                           x, batch, out, sums, cnts, N);
        hipLaunchKernelGGL(activs_finalize_kernel, dim3(1), dim3(1024), 0, stream,
                           sums, cnts, batch, N, out + (size_t)N * D);
    }
}

// Round 12
// 401.589 us; speedup vs baseline: 1.0165x; 1.0165x over previous
//
#include <hip/hip_runtime.h>

#define NUM_GRAPHS 1024
#define D 256

// ---------------------------------------------------------------------------
// init: zero the 1024 segment sums + 1024 counts each call.
// ---------------------------------------------------------------------------
__global__ void activs_init_kernel(float* __restrict__ sums, float* __restrict__ cnts) {
    int i = blockIdx.x * blockDim.x + threadIdx.x;
    if (i < NUM_GRAPHS) {
        sums[i] = 0.0f;
        cnts[i] = 0.0f;
    }
}

__device__ __forceinline__ float sq4(const float4 v) {
    return v.x * v.x + v.y * v.y + v.z * v.z + v.w * v.w;
}

// 8 rows per wave-iteration, FULL-ROW mapping: lane owns float4 slot `lane`
// of every row; one load/store instruction = one 1KB contiguous row segment.
struct Rows8 {
    float4 v0, v1, v2, v3, v4, v5, v6, v7;
};

__device__ __forceinline__ void load8(Rows8& R, const float* __restrict__ x,
                                      int r, int lane) {
    R.v0 = ((const float4*)(x + (size_t)(r + 0) * D))[lane];
    R.v1 = ((const float4*)(x + (size_t)(r + 1) * D))[lane];
    R.v2 = ((const float4*)(x + (size_t)(r + 2) * D))[lane];
    R.v3 = ((const float4*)(x + (size_t)(r + 3) * D))[lane];
    R.v4 = ((const float4*)(x + (size_t)(r + 4) * D))[lane];
    R.v5 = ((const float4*)(x + (size_t)(r + 5) * D))[lane];
    R.v6 = ((const float4*)(x + (size_t)(r + 6) * D))[lane];
    R.v7 = ((const float4*)(x + (size_t)(r + 7) * D))[lane];
}

__device__ __forceinline__ void store8(const Rows8& R, float* __restrict__ out,
                                       int r, int lane) {
    ((float4*)(out + (size_t)(r + 0) * D))[lane] = R.v0;
    ((float4*)(out + (size_t)(r + 1) * D))[lane] = R.v1;
    ((float4*)(out + (size_t)(r + 2) * D))[lane] = R.v2;
    ((float4*)(out + (size_t)(r + 3) * D))[lane] = R.v3;
    ((float4*)(out + (size_t)(r + 4) * D))[lane] = R.v4;
    ((float4*)(out + (size_t)(r + 5) * D))[lane] = R.v5;
    ((float4*)(out + (size_t)(r + 6) * D))[lane] = R.v6;
    ((float4*)(out + (size_t)(r + 7) * D))[lane] = R.v7;
}

// ---------------------------------------------------------------------------
// PHASE B (R10 structure, REDUCED GRID): full-row streaming, 8 rows/iter,
// depth-1 prefetch. Launched with 512 blocks (2 blocks/CU, 2048 waves) —
// 4x fewer concurrent DRAM streams than the 2048-block default, while
// keeping 16MB of reads in flight (>> the ~5.7MB Little's-law floor).
// ---------------------------------------------------------------------------
__global__ __launch_bounds__(256) void activs_stream_kernel(
        const float* __restrict__ x, float* __restrict__ out,
        float* __restrict__ norms, int N) {
    const int lane = threadIdx.x & 63;
    const int waveId = (blockIdx.x * blockDim.x + threadIdx.x) >> 6;
    const int totalWaves = (gridDim.x * blockDim.x) >> 6;
    const int stride = totalWaves * 8;

    const int Nq = N & ~7;            // multiple-of-8 prefix (N=1e6 -> Nq==N)

    int r = waveId * 8;
    if (r < Nq) {
        Rows8 cur;
        load8(cur, x, r, lane);

        while (true) {
            const int rn = r + stride;
            const bool more = (rn < Nq);
            Rows8 nxt;
            if (more) load8(nxt, x, rn, lane);   // prefetch stays in flight

            store8(cur, out, r, lane);           // waits cur loads only

            float s0 = sq4(cur.v0), s1 = sq4(cur.v1);
            float s2 = sq4(cur.v2), s3 = sq4(cur.v3);
            float s4 = sq4(cur.v4), s5 = sq4(cur.v5);
            float s6 = sq4(cur.v6), s7 = sq4(cur.v7);
            #pragma unroll
            for (int m = 1; m <= 32; m <<= 1) {
                s0 += __shfl_xor(s0, m, 64);
                s1 += __shfl_xor(s1, m, 64);
                s2 += __shfl_xor(s2, m, 64);
                s3 += __shfl_xor(s3, m, 64);
                s4 += __shfl_xor(s4, m, 64);
                s5 += __shfl_xor(s5, m, 64);
                s6 += __shfl_xor(s6, m, 64);
                s7 += __shfl_xor(s7, m, 64);
            }
            // route row j's (wave-uniform) sum to lane j, one coalesced store
            float nv = s0;
            nv = (lane == 1) ? s1 : nv;
            nv = (lane == 2) ? s2 : nv;
            nv = (lane == 3) ? s3 : nv;
            nv = (lane == 4) ? s4 : nv;
            nv = (lane == 5) ? s5 : nv;
            nv = (lane == 6) ? s6 : nv;
            nv = (lane == 7) ? s7 : nv;
            if (lane < 8) norms[r + lane] = sqrtf(nv);

            if (!more) break;
            cur = nxt;
            r = rn;
        }
    }

    // tail rows (only if N % 8 != 0; dead for N=1e6)
    if (waveId == 0) {
        for (int t = Nq; t < N; ++t) {
            const float4 v = ((const float4*)(x + (size_t)t * D))[lane];
            ((float4*)(out + (size_t)t * D))[lane] = v;
            float s = sq4(v);
            #pragma unroll
            for (int m = 32; m; m >>= 1) s += __shfl_xor(s, m, 64);
            if (lane == 0) norms[t] = sqrtf(s);
        }
    }
}

// ---------------------------------------------------------------------------
// PHASE C: segment reduce over norms (R8-proven). Each block owns 1024
// consecutive rows; each thread run-length-reduces 4 consecutive rows
// (batch sorted) into LDS bins; block flushes non-empty bins with global
// atomics (~2 pairs/block).
// ---------------------------------------------------------------------------
__global__ __launch_bounds__(256) void activs_segred_kernel(
        const float* __restrict__ norms, const int* __restrict__ batch,
        float* __restrict__ sums, float* __restrict__ cnts, int N) {
    __shared__ float lsum[NUM_GRAPHS];
    __shared__ float lcnt[NUM_GRAPHS];
    const int tid = threadIdx.x;

    for (int i = tid; i < NUM_GRAPHS; i += 256) {
        lsum[i] = 0.0f;
        lcnt[i] = 0.0f;
    }
    __syncthreads();

    const int base = blockIdx.x * 1024 + tid * 4;
    if (base < N) {
        const float4 nv = *(const float4*)(norms + base);
        const int4 bv = *(const int4*)(batch + base);
        const float n[4] = {nv.x, nv.y, nv.z, nv.w};
        const int b[4] = {bv.x, bv.y, bv.z, bv.w};
        int seg = b[0];
        float rs = n[0], rc = 1.0f;
        #pragma unroll
        for (int k = 1; k < 4; ++k) {
            if (b[k] == seg) { rs += n[k]; rc += 1.0f; }
            else {
                atomicAdd(&lsum[seg], rs);
                atomicAdd(&lcnt[seg], rc);
                seg = b[k]; rs = n[k]; rc = 1.0f;
            }
        }
        atomicAdd(&lsum[seg], rs);
        atomicAdd(&lcnt[seg], rc);
    }
    __syncthreads();

    for (int i = tid; i < NUM_GRAPHS; i += 256) {
        if (lcnt[i] != 0.0f) {
            atomicAdd(&sums[i], lsum[i]);
            atomicAdd(&cnts[i], lcnt[i]);
        }
    }
}

// ---------------------------------------------------------------------------
// FALLBACK (fused, full-row): used only if ws can't hold norms.
// ---------------------------------------------------------------------------
__global__ __launch_bounds__(256) void activs_fused_kernel(
        const float* __restrict__ x, const int* __restrict__ batch,
        float* __restrict__ out, float* __restrict__ sums,
        float* __restrict__ cnts, int N) {
    const int lane = threadIdx.x & 63;
    const int waveId = (blockIdx.x * blockDim.x + threadIdx.x) >> 6;
    const int totalWaves = (gridDim.x * blockDim.x) >> 6;
    const int stride = totalWaves * 8;
    const int Nq = N & ~7;

    int r = waveId * 8;
    if (r < Nq) {
        Rows8 cur;
        load8(cur, x, r, lane);
        int4 w0 = ((const int4*)(batch + r))[0];
        int4 w1 = ((const int4*)(batch + r))[1];

        while (true) {
            const int rn = r + stride;
            const bool more = (rn < Nq);
            Rows8 nxt;
            int4 nw0, nw1;
            if (more) {
                load8(nxt, x, rn, lane);
                nw0 = ((const int4*)(batch + rn))[0];
                nw1 = ((const int4*)(batch + rn))[1];
            }
            store8(cur, out, r, lane);

            float s0 = sq4(cur.v0), s1 = sq4(cur.v1);
            float s2 = sq4(cur.v2), s3 = sq4(cur.v3);
            float s4 = sq4(cur.v4), s5 = sq4(cur.v5);
            float s6 = sq4(cur.v6), s7 = sq4(cur.v7);
            #pragma unroll
            for (int m = 1; m <= 32; m <<= 1) {
                s0 += __shfl_xor(s0, m, 64);
                s1 += __shfl_xor(s1, m, 64);
                s2 += __shfl_xor(s2, m, 64);
                s3 += __shfl_xor(s3, m, 64);
                s4 += __shfl_xor(s4, m, 64);
                s5 += __shfl_xor(s5, m, 64);
                s6 += __shfl_xor(s6, m, 64);
                s7 += __shfl_xor(s7, m, 64);
            }

            if (lane == 0) {
                const float n[8] = {sqrtf(s0), sqrtf(s1), sqrtf(s2), sqrtf(s3),
                                    sqrtf(s4), sqrtf(s5), sqrtf(s6), sqrtf(s7)};
                const int b[8] = {w0.x, w0.y, w0.z, w0.w, w1.x, w1.y, w1.z, w1.w};
                int seg = b[0];
                float rs = n[0], rc = 1.0f;
                #pragma unroll
                for (int k = 1; k < 8; ++k) {
                    if (b[k] == seg) { rs += n[k]; rc += 1.0f; }
                    else {
                        atomicAdd(&sums[seg], rs);
                        atomicAdd(&cnts[seg], rc);
                        seg = b[k]; rs = n[k]; rc = 1.0f;
                    }
                }
                atomicAdd(&sums[seg], rs);
                atomicAdd(&cnts[seg], rc);
            }

            if (!more) break;
            cur = nxt; w0 = nw0; w1 = nw1; r = rn;
        }
    }
    if (waveId == 0) {
        for (int t = Nq; t < N; ++t) {
            const float4 v = ((const float4*)(x + (size_t)t * D))[lane];
            ((float4*)(out + (size_t)t * D))[lane] = v;
            float s = sq4(v);
            #pragma unroll
            for (int m = 32; m; m >>= 1) s += __shfl_xor(s, m, 64);
            if (lane == 0) {
                atomicAdd(&sums[batch[t]], sqrtf(s));
                atomicAdd(&cnts[batch[t]], 1.0f);
            }
        }
    }
}

// ---------------------------------------------------------------------------
// finalize: per_graph = sum/count; mask i < bmax; mean / (bmax + 1).
// ---------------------------------------------------------------------------
__global__ __launch_bounds__(1024) void activs_finalize_kernel(
        const float* __restrict__ sums, const float* __restrict__ cnts,
        const int* __restrict__ batch, int N, float* __restrict__ out_scalar) {
    __shared__ float red[16];
    const int i = threadIdx.x;
    const int lane = i & 63;
    const int w = i >> 6;

    const float bmax = (float)batch[N - 1];

    float c = cnts[i];
    float pg = (c > 0.0f) ? (sums[i] / c) : 0.0f;
    float val = (((float)i) < bmax) ? pg : 0.0f;

    #pragma unroll
    for (int m = 32; m; m >>= 1) val += __shfl_xor(val, m, 64);
    if (lane == 0) red[w] = val;
    __syncthreads();

    if (w == 0) {
        float v = (lane < 16) ? red[lane] : 0.0f;
        #pragma unroll
        for (int m = 8; m; m >>= 1) v += __shfl_xor(v, m, 64);
        if (lane == 0) out_scalar[0] = v / (bmax + 1.0f);
    }
}

// ---------------------------------------------------------------------------
extern "C" void kernel_launch(void* const* d_in, const int* in_sizes, int n_in,
                              void* d_out, int out_size, void* d_ws, size_t ws_size,
                              hipStream_t stream) {
    const float* x = (const float*)d_in[0];
    const int* batch = (const int*)d_in[1];
    float* out = (float*)d_out;

    const int N = in_sizes[1];                 // 1,000,000 rows (D = 256)

    const size_t need_norm = ((size_t)N + 2 * NUM_GRAPHS) * sizeof(float);

    if (ws_size >= need_norm) {
        float* norms = (float*)d_ws;           // [N]
        float* sums = norms + N;               // [1024]
        float* cnts = sums + NUM_GRAPHS;       // [1024]

        hipLaunchKernelGGL(activs_init_kernel, dim3(4), dim3(256), 0, stream, sums, cnts);
        // 512 blocks = 2 blocks/CU, 2048 waves: 4x fewer concurrent DRAM
        // streams than the 2048-block default (TLP axis experiment).
        hipLaunchKernelGGL(activs_stream_kernel, dim3(512), dim3(256), 0, stream,
                           x, out, norms, N);
        hipLaunchKernelGGL(activs_segred_kernel, dim3((N + 1023) / 1024), dim3(256),
                           0, stream, norms, batch, sums, cnts, N);
        hipLaunchKernelGGL(activs_finalize_kernel, dim3(1), dim3(1024), 0, stream,
                           sums, cnts, batch, N, out + (size_t)N * D);
    } else {
        float* sums = (float*)d_ws;            // [1024]
        float* cnts = sums + NUM_GRAPHS;       // [1024]

        hipLaunchKernelGGL(activs_init_kernel, dim3(4), dim3(256), 0, stream, sums, cnts);
        hipLaunchKernelGGL(activs_fused_kernel, dim3(2048), dim3(256), 0, stream,
                           x, batch, out, sums, cnts, N);
        hipLaunchKernelGGL(activs_finalize_kernel, dim3(1), dim3(1024), 0, stream,
                           sums, cnts, batch, N, out + (size_t)N * D);
    }
}

// Round 13
// 378.087 us; speedup vs baseline: 1.0797x; 1.0622x over previous
//
#include <hip/hip_runtime.h>

#define NUM_GRAPHS 1024
#define D 256

// clang native vector type — required by __builtin_nontemporal_{load,store}
// (HIP_vector_type<float,4> is a struct and is rejected). Supports .x/.y/.z/.w.
typedef float f4 __attribute__((ext_vector_type(4)));

// ---------------------------------------------------------------------------
// init: zero the 1024 segment sums + 1024 counts each call.
// ---------------------------------------------------------------------------
__global__ void activs_init_kernel(float* __restrict__ sums, float* __restrict__ cnts) {
    int i = blockIdx.x * blockDim.x + threadIdx.x;
    if (i < NUM_GRAPHS) {
        sums[i] = 0.0f;
        cnts[i] = 0.0f;
    }
}

__device__ __forceinline__ float sq4v(const f4 v) {
    return v.x * v.x + v.y * v.y + v.z * v.z + v.w * v.w;
}

// 8 rows per wave-iteration, FULL-ROW mapping: lane owns float4 slot `lane`
// of every row; one load/store instruction = one 1KB contiguous row segment.
// NON-TEMPORAL on both sides: x is read-once (>L3), out is write-once
// (never re-read) — avoid write-allocate/cache pollution on 2GB of
// strictly-streaming traffic.
struct Rows8 {
    f4 v0, v1, v2, v3, v4, v5, v6, v7;
};

__device__ __forceinline__ void load8(Rows8& R, const float* __restrict__ x,
                                      int r, int lane) {
    R.v0 = __builtin_nontemporal_load((const f4*)(x + (size_t)(r + 0) * D) + lane);
    R.v1 = __builtin_nontemporal_load((const f4*)(x + (size_t)(r + 1) * D) + lane);
    R.v2 = __builtin_nontemporal_load((const f4*)(x + (size_t)(r + 2) * D) + lane);
    R.v3 = __builtin_nontemporal_load((const f4*)(x + (size_t)(r + 3) * D) + lane);
    R.v4 = __builtin_nontemporal_load((const f4*)(x + (size_t)(r + 4) * D) + lane);
    R.v5 = __builtin_nontemporal_load((const f4*)(x + (size_t)(r + 5) * D) + lane);
    R.v6 = __builtin_nontemporal_load((const f4*)(x + (size_t)(r + 6) * D) + lane);
    R.v7 = __builtin_nontemporal_load((const f4*)(x + (size_t)(r + 7) * D) + lane);
}

__device__ __forceinline__ void store8(const Rows8& R, float* __restrict__ out,
                                       int r, int lane) {
    __builtin_nontemporal_store(R.v0, (f4*)(out + (size_t)(r + 0) * D) + lane);
    __builtin_nontemporal_store(R.v1, (f4*)(out + (size_t)(r + 1) * D) + lane);
    __builtin_nontemporal_store(R.v2, (f4*)(out + (size_t)(r + 2) * D) + lane);
    __builtin_nontemporal_store(R.v3, (f4*)(out + (size_t)(r + 3) * D) + lane);
    __builtin_nontemporal_store(R.v4, (f4*)(out + (size_t)(r + 4) * D) + lane);
    __builtin_nontemporal_store(R.v5, (f4*)(out + (size_t)(r + 5) * D) + lane);
    __builtin_nontemporal_store(R.v6, (f4*)(out + (size_t)(r + 6) * D) + lane);
    __builtin_nontemporal_store(R.v7, (f4*)(out + (size_t)(r + 7) * D) + lane);
}

// ---------------------------------------------------------------------------
// PHASE B (R12 structure + NT): full-row streaming, 8 rows/iter, depth-1
// prefetch, 512 blocks. Only change vs R12: non-temporal loads/stores.
// ---------------------------------------------------------------------------
__global__ __launch_bounds__(256) void activs_stream_kernel(
        const float* __restrict__ x, float* __restrict__ out,
        float* __restrict__ norms, int N) {
    const int lane = threadIdx.x & 63;
    const int waveId = (blockIdx.x * blockDim.x + threadIdx.x) >> 6;
    const int totalWaves = (gridDim.x * blockDim.x) >> 6;
    const int stride = totalWaves * 8;

    const int Nq = N & ~7;            // multiple-of-8 prefix (N=1e6 -> Nq==N)

    int r = waveId * 8;
    if (r < Nq) {
        Rows8 cur;
        load8(cur, x, r, lane);

        while (true) {
            const int rn = r + stride;
            const bool more = (rn < Nq);
            Rows8 nxt;
            if (more) load8(nxt, x, rn, lane);   // prefetch stays in flight

            store8(cur, out, r, lane);           // waits cur loads only

            float s0 = sq4v(cur.v0), s1 = sq4v(cur.v1);
            float s2 = sq4v(cur.v2), s3 = sq4v(cur.v3);
            float s4 = sq4v(cur.v4), s5 = sq4v(cur.v5);
            float s6 = sq4v(cur.v6), s7 = sq4v(cur.v7);
            #pragma unroll
            for (int m = 1; m <= 32; m <<= 1) {
                s0 += __shfl_xor(s0, m, 64);
                s1 += __shfl_xor(s1, m, 64);
                s2 += __shfl_xor(s2, m, 64);
                s3 += __shfl_xor(s3, m, 64);
                s4 += __shfl_xor(s4, m, 64);
                s5 += __shfl_xor(s5, m, 64);
                s6 += __shfl_xor(s6, m, 64);
                s7 += __shfl_xor(s7, m, 64);
            }
            // route row j's (wave-uniform) sum to lane j, one coalesced store
            float nv = s0;
            nv = (lane == 1) ? s1 : nv;
            nv = (lane == 2) ? s2 : nv;
            nv = (lane == 3) ? s3 : nv;
            nv = (lane == 4) ? s4 : nv;
            nv = (lane == 5) ? s5 : nv;
            nv = (lane == 6) ? s6 : nv;
            nv = (lane == 7) ? s7 : nv;
            if (lane < 8) norms[r + lane] = sqrtf(nv);

            if (!more) break;
            cur = nxt;
            r = rn;
        }
    }

    // tail rows (only if N % 8 != 0; dead for N=1e6)
    if (waveId == 0) {
        for (int t = Nq; t < N; ++t) {
            const f4 v = ((const f4*)(x + (size_t)t * D))[lane];
            ((f4*)(out + (size_t)t * D))[lane] = v;
            float s = sq4v(v);
            #pragma unroll
            for (int m = 32; m; m >>= 1) s += __shfl_xor(s, m, 64);
            if (lane == 0) norms[t] = sqrtf(s);
        }
    }
}

// ---------------------------------------------------------------------------
// PHASE C: segment reduce over norms (R8-proven). Each block owns 1024
// consecutive rows; each thread run-length-reduces 4 consecutive rows
// (batch sorted) into LDS bins; block flushes non-empty bins with global
// atomics (~2 pairs/block).
// ---------------------------------------------------------------------------
__global__ __launch_bounds__(256) void activs_segred_kernel(
        const float* __restrict__ norms, const int* __restrict__ batch,
        float* __restrict__ sums, float* __restrict__ cnts, int N) {
    __shared__ float lsum[NUM_GRAPHS];
    __shared__ float lcnt[NUM_GRAPHS];
    const int tid = threadIdx.x;

    for (int i = tid; i < NUM_GRAPHS; i += 256) {
        lsum[i] = 0.0f;
        lcnt[i] = 0.0f;
    }
    __syncthreads();

    const int base = blockIdx.x * 1024 + tid * 4;
    if (base < N) {
        const float4 nv = *(const float4*)(norms + base);
        const int4 bv = *(const int4*)(batch + base);
        const float n[4] = {nv.x, nv.y, nv.z, nv.w};
        const int b[4] = {bv.x, bv.y, bv.z, bv.w};
        int seg = b[0];
        float rs = n[0], rc = 1.0f;
        #pragma unroll
        for (int k = 1; k < 4; ++k) {
            if (b[k] == seg) { rs += n[k]; rc += 1.0f; }
            else {
                atomicAdd(&lsum[seg], rs);
                atomicAdd(&lcnt[seg], rc);
                seg = b[k]; rs = n[k]; rc = 1.0f;
            }
        }
        atomicAdd(&lsum[seg], rs);
        atomicAdd(&lcnt[seg], rc);
    }
    __syncthreads();

    for (int i = tid; i < NUM_GRAPHS; i += 256) {
        if (lcnt[i] != 0.0f) {
            atomicAdd(&sums[i], lsum[i]);
            atomicAdd(&cnts[i], lcnt[i]);
        }
    }
}

// ---------------------------------------------------------------------------
// FALLBACK (fused, full-row, plain loads): used only if ws can't hold norms.
// ---------------------------------------------------------------------------
__global__ __launch_bounds__(256) void activs_fused_kernel(
        const float* __restrict__ x, const int* __restrict__ batch,
        float* __restrict__ out, float* __restrict__ sums,
        float* __restrict__ cnts, int N) {
    const int lane = threadIdx.x & 63;
    const int waveId = (blockIdx.x * blockDim.x + threadIdx.x) >> 6;
    const int totalWaves = (gridDim.x * blockDim.x) >> 6;
    const int stride = totalWaves * 8;
    const int Nq = N & ~7;

    int r = waveId * 8;
    if (r < Nq) {
        Rows8 cur;
        load8(cur, x, r, lane);
        int4 w0 = ((const int4*)(batch + r))[0];
        int4 w1 = ((const int4*)(batch + r))[1];

        while (true) {
            const int rn = r + stride;
            const bool more = (rn < Nq);
            Rows8 nxt;
            int4 nw0, nw1;
            if (more) {
                load8(nxt, x, rn, lane);
                nw0 = ((const int4*)(batch + rn))[0];
                nw1 = ((const int4*)(batch + rn))[1];
            }
            store8(cur, out, r, lane);

            float s0 = sq4v(cur.v0), s1 = sq4v(cur.v1);
            float s2 = sq4v(cur.v2), s3 = sq4v(cur.v3);
            float s4 = sq4v(cur.v4), s5 = sq4v(cur.v5);
            float s6 = sq4v(cur.v6), s7 = sq4v(cur.v7);
            #pragma unroll
            for (int m = 1; m <= 32; m <<= 1) {
                s0 += __shfl_xor(s0, m, 64);
                s1 += __shfl_xor(s1, m, 64);
                s2 += __shfl_xor(s2, m, 64);
                s3 += __shfl_xor(s3, m, 64);
                s4 += __shfl_xor(s4, m, 64);
                s5 += __shfl_xor(s5, m, 64);
                s6 += __shfl_xor(s6, m, 64);
                s7 += __shfl_xor(s7, m, 64);
            }

            if (lane == 0) {
                const float n[8] = {sqrtf(s0), sqrtf(s1), sqrtf(s2), sqrtf(s3),
                                    sqrtf(s4), sqrtf(s5), sqrtf(s6), sqrtf(s7)};
                const int b[8] = {w0.x, w0.y, w0.z, w0.w, w1.x, w1.y, w1.z, w1.w};
                int seg = b[0];
                float rs = n[0], rc = 1.0f;
                #pragma unroll
                for (int k = 1; k < 8; ++k) {
                    if (b[k] == seg) { rs += n[k]; rc += 1.0f; }
                    else {
                        atomicAdd(&sums[seg], rs);
                        atomicAdd(&cnts[seg], rc);
                        seg = b[k]; rs = n[k]; rc = 1.0f;
                    }
                }
                atomicAdd(&sums[seg], rs);
                atomicAdd(&cnts[seg], rc);
            }

            if (!more) break;
            cur = nxt; w0 = nw0; w1 = nw1; r = rn;
        }
    }
    if (waveId == 0) {
        for (int t = Nq; t < N; ++t) {
            const f4 v = ((const f4*)(x + (size_t)t * D))[lane];
            ((f4*)(out + (size_t)t * D))[lane] = v;
            float s = sq4v(v);
            #pragma unroll
            for (int m = 32; m; m >>= 1) s += __shfl_xor(s, m, 64);
            if (lane == 0) {
                atomicAdd(&sums[batch[t]], sqrtf(s));
                atomicAdd(&cnts[batch[t]], 1.0f);
            }
        }
    }
}

// ---------------------------------------------------------------------------
// finalize: per_graph = sum/count; mask i < bmax; mean / (bmax + 1).
// ---------------------------------------------------------------------------
__global__ __launch_bounds__(1024) void activs_finalize_kernel(
        const float* __restrict__ sums, const float* __restrict__ cnts,
        const int* __restrict__ batch, int N, float* __restrict__ out_scalar) {
    __shared__ float red[16];
    const int i = threadIdx.x;
    const int lane = i & 63;
    const int w = i >> 6;

    const float bmax = (float)batch[N - 1];

    float c = cnts[i];
    float pg = (c > 0.0f) ? (sums[i] / c) : 0.0f;
    float val = (((float)i) < bmax) ? pg : 0.0f;

    #pragma unroll
    for (int m = 32; m; m >>= 1) val += __shfl_xor(val, m, 64);
    if (lane == 0) red[w] = val;
    __syncthreads();

    if (w == 0) {
        float v = (lane < 16) ? red[lane] : 0.0f;
        #pragma unroll
        for (int m = 8; m; m >>= 1) v += __shfl_xor(v, m, 64);
        if (lane == 0) out_scalar[0] = v / (bmax + 1.0f);
    }
}

// ---------------------------------------------------------------------------
extern "C" void kernel_launch(void* const* d_in, const int* in_sizes, int n_in,
                              void* d_out, int out_size, void* d_ws, size_t ws_size,
                              hipStream_t stream) {
    const float* x = (const float*)d_in[0];
    const int* batch = (const int*)d_in[1];
    float* out = (float*)d_out;

    const int N = in_sizes[1];                 // 1,000,000 rows (D = 256)

    const size_t need_norm = ((size_t)N + 2 * NUM_GRAPHS) * sizeof(float);

    if (ws_size >= need_norm) {
        float* norms = (float*)d_ws;           // [N]
        float* sums = norms + N;               // [1024]
        float* cnts = sums + NUM_GRAPHS;       // [1024]

        hipLaunchKernelGGL(activs_init_kernel, dim3(4), dim3(256), 0, stream, sums, cnts);
        hipLaunchKernelGGL(activs_stream_kernel, dim3(512), dim3(256), 0, stream,
                           x, out, norms, N);
        hipLaunchKernelGGL(activs_segred_kernel, dim3((N + 1023) / 1024), dim3(256),
                           0, stream, norms, batch, sums, cnts, N);
        hipLaunchKernelGGL(activs_finalize_kernel, dim3(1), dim3(1024), 0, stream,
                           sums, cnts, batch, N, out + (size_t)N * D);
    } else {
        float* sums = (float*)d_ws;            // [1024]
        float* cnts = sums + NUM_GRAPHS;       // [1024]

        hipLaunchKernelGGL(activs_init_kernel, dim3(4), dim3(256), 0, stream, sums, cnts);
        hipLaunchKernelGGL(activs_fused_kernel, dim3(2048), dim3(256), 0, stream,
                           x, batch, out, sums, cnts, N);
        hipLaunchKernelGGL(activs_finalize_kernel, dim3(1), dim3(1024), 0, stream,
                           sums, cnts, batch, N, out + (size_t)N * D);
    }
}

// Round 14
// 376.992 us; speedup vs baseline: 1.0829x; 1.0029x over previous
//
#include <hip/hip_runtime.h>

#define NUM_GRAPHS 1024
#define D 256

// clang native vector type — required by __builtin_nontemporal_{load,store}
// (HIP_vector_type<float,4> is a struct and is rejected). Supports .x/.y/.z/.w.
typedef float f4 __attribute__((ext_vector_type(4)));

// ---------------------------------------------------------------------------
// init: zero the 1024 segment sums + 1024 counts each call.
// ---------------------------------------------------------------------------
__global__ void activs_init_kernel(float* __restrict__ sums, float* __restrict__ cnts) {
    int i = blockIdx.x * blockDim.x + threadIdx.x;
    if (i < NUM_GRAPHS) {
        sums[i] = 0.0f;
        cnts[i] = 0.0f;
    }
}

__device__ __forceinline__ float sq4v(const f4 v) {
    return v.x * v.x + v.y * v.y + v.z * v.z + v.w * v.w;
}

// 8 rows per wave-iteration, FULL-ROW mapping: lane owns float4 slot `lane`
// of every row; one load/store instruction = one 1KB contiguous row segment.
// NON-TEMPORAL on both sides (R13: -23.5us win).
struct Rows8 {
    f4 v0, v1, v2, v3, v4, v5, v6, v7;
};

__device__ __forceinline__ void load8(Rows8& R, const float* __restrict__ x,
                                      int r, int lane) {
    R.v0 = __builtin_nontemporal_load((const f4*)(x + (size_t)(r + 0) * D) + lane);
    R.v1 = __builtin_nontemporal_load((const f4*)(x + (size_t)(r + 1) * D) + lane);
    R.v2 = __builtin_nontemporal_load((const f4*)(x + (size_t)(r + 2) * D) + lane);
    R.v3 = __builtin_nontemporal_load((const f4*)(x + (size_t)(r + 3) * D) + lane);
    R.v4 = __builtin_nontemporal_load((const f4*)(x + (size_t)(r + 4) * D) + lane);
    R.v5 = __builtin_nontemporal_load((const f4*)(x + (size_t)(r + 5) * D) + lane);
    R.v6 = __builtin_nontemporal_load((const f4*)(x + (size_t)(r + 6) * D) + lane);
    R.v7 = __builtin_nontemporal_load((const f4*)(x + (size_t)(r + 7) * D) + lane);
}

__device__ __forceinline__ void store8(const Rows8& R, float* __restrict__ out,
                                       int r, int lane) {
    __builtin_nontemporal_store(R.v0, (f4*)(out + (size_t)(r + 0) * D) + lane);
    __builtin_nontemporal_store(R.v1, (f4*)(out + (size_t)(r + 1) * D) + lane);
    __builtin_nontemporal_store(R.v2, (f4*)(out + (size_t)(r + 2) * D) + lane);
    __builtin_nontemporal_store(R.v3, (f4*)(out + (size_t)(r + 3) * D) + lane);
    __builtin_nontemporal_store(R.v4, (f4*)(out + (size_t)(r + 4) * D) + lane);
    __builtin_nontemporal_store(R.v5, (f4*)(out + (size_t)(r + 5) * D) + lane);
    __builtin_nontemporal_store(R.v6, (f4*)(out + (size_t)(r + 6) * D) + lane);
    __builtin_nontemporal_store(R.v7, (f4*)(out + (size_t)(r + 7) * D) + lane);
}

// ---------------------------------------------------------------------------
// PHASE B (R13 + grid re-probe): full-row NT streaming, 8 rows/iter, depth-1
// prefetch. Single change vs R13: 2048 blocks instead of 512 (TLP axis
// re-probed under NT semantics — R12's null was measured with
// cache-allocating writes, a different binding constraint).
// ---------------------------------------------------------------------------
__global__ __launch_bounds__(256) void activs_stream_kernel(
        const float* __restrict__ x, float* __restrict__ out,
        float* __restrict__ norms, int N) {
    const int lane = threadIdx.x & 63;
    const int waveId = (blockIdx.x * blockDim.x + threadIdx.x) >> 6;
    const int totalWaves = (gridDim.x * blockDim.x) >> 6;
    const int stride = totalWaves * 8;

    const int Nq = N & ~7;            // multiple-of-8 prefix (N=1e6 -> Nq==N)

    int r = waveId * 8;
    if (r < Nq) {
        Rows8 cur;
        load8(cur, x, r, lane);

        while (true) {
            const int rn = r + stride;
            const bool more = (rn < Nq);
            Rows8 nxt;
            if (more) load8(nxt, x, rn, lane);   // prefetch stays in flight

            store8(cur, out, r, lane);           // waits cur loads only

            float s0 = sq4v(cur.v0), s1 = sq4v(cur.v1);
            float s2 = sq4v(cur.v2), s3 = sq4v(cur.v3);
            float s4 = sq4v(cur.v4), s5 = sq4v(cur.v5);
            float s6 = sq4v(cur.v6), s7 = sq4v(cur.v7);
            #pragma unroll
            for (int m = 1; m <= 32; m <<= 1) {
                s0 += __shfl_xor(s0, m, 64);
                s1 += __shfl_xor(s1, m, 64);
                s2 += __shfl_xor(s2, m, 64);
                s3 += __shfl_xor(s3, m, 64);
                s4 += __shfl_xor(s4, m, 64);
                s5 += __shfl_xor(s5, m, 64);
                s6 += __shfl_xor(s6, m, 64);
                s7 += __shfl_xor(s7, m, 64);
            }
            // route row j's (wave-uniform) sum to lane j, one coalesced store
            float nv = s0;
            nv = (lane == 1) ? s1 : nv;
            nv = (lane == 2) ? s2 : nv;
            nv = (lane == 3) ? s3 : nv;
            nv = (lane == 4) ? s4 : nv;
            nv = (lane == 5) ? s5 : nv;
            nv = (lane == 6) ? s6 : nv;
            nv = (lane == 7) ? s7 : nv;
            if (lane < 8) norms[r + lane] = sqrtf(nv);

            if (!more) break;
            cur = nxt;
            r = rn;
        }
    }

    // tail rows (only if N % 8 != 0; dead for N=1e6)
    if (waveId == 0) {
        for (int t = Nq; t < N; ++t) {
            const f4 v = ((const f4*)(x + (size_t)t * D))[lane];
            ((f4*)(out + (size_t)t * D))[lane] = v;
            float s = sq4v(v);
            #pragma unroll
            for (int m = 32; m; m >>= 1) s += __shfl_xor(s, m, 64);
            if (lane == 0) norms[t] = sqrtf(s);
        }
    }
}

// ---------------------------------------------------------------------------
// PHASE C: segment reduce over norms (R8-proven). Each block owns 1024
// consecutive rows; each thread run-length-reduces 4 consecutive rows
// (batch sorted) into LDS bins; block flushes non-empty bins with global
// atomics (~2 pairs/block).
// ---------------------------------------------------------------------------
__global__ __launch_bounds__(256) void activs_segred_kernel(
        const float* __restrict__ norms, const int* __restrict__ batch,
        float* __restrict__ sums, float* __restrict__ cnts, int N) {
    __shared__ float lsum[NUM_GRAPHS];
    __shared__ float lcnt[NUM_GRAPHS];
    const int tid = threadIdx.x;

    for (int i = tid; i < NUM_GRAPHS; i += 256) {
        lsum[i] = 0.0f;
        lcnt[i] = 0.0f;
    }
    __syncthreads();

    const int base = blockIdx.x * 1024 + tid * 4;
    if (base < N) {
        const float4 nv = *(const float4*)(norms + base);
        const int4 bv = *(const int4*)(batch + base);
        const float n[4] = {nv.x, nv.y, nv.z, nv.w};
        const int b[4] = {bv.x, bv.y, bv.z, bv.w};
        int seg = b[0];
        float rs = n[0], rc = 1.0f;
        #pragma unroll
        for (int k = 1; k < 4; ++k) {
            if (b[k] == seg) { rs += n[k]; rc += 1.0f; }
            else {
                atomicAdd(&lsum[seg], rs);
                atomicAdd(&lcnt[seg], rc);
                seg = b[k]; rs = n[k]; rc = 1.0f;
            }
        }
        atomicAdd(&lsum[seg], rs);
        atomicAdd(&lcnt[seg], rc);
    }
    __syncthreads();

    for (int i = tid; i < NUM_GRAPHS; i += 256) {
        if (lcnt[i] != 0.0f) {
            atomicAdd(&sums[i], lsum[i]);
            atomicAdd(&cnts[i], lcnt[i]);
        }
    }
}

// ---------------------------------------------------------------------------
// FALLBACK (fused, full-row): used only if ws can't hold norms.
// ---------------------------------------------------------------------------
__global__ __launch_bounds__(256) void activs_fused_kernel(
        const float* __restrict__ x, const int* __restrict__ batch,
        float* __restrict__ out, float* __restrict__ sums,
        float* __restrict__ cnts, int N) {
    const int lane = threadIdx.x & 63;
    const int waveId = (blockIdx.x * blockDim.x + threadIdx.x) >> 6;
    const int totalWaves = (gridDim.x * blockDim.x) >> 6;
    const int stride = totalWaves * 8;
    const int Nq = N & ~7;

    int r = waveId * 8;
    if (r < Nq) {
        Rows8 cur;
        load8(cur, x, r, lane);
        int4 w0 = ((const int4*)(batch + r))[0];
        int4 w1 = ((const int4*)(batch + r))[1];

        while (true) {
            const int rn = r + stride;
            const bool more = (rn < Nq);
            Rows8 nxt;
            int4 nw0, nw1;
            if (more) {
                load8(nxt, x, rn, lane);
                nw0 = ((const int4*)(batch + rn))[0];
                nw1 = ((const int4*)(batch + rn))[1];
            }
            store8(cur, out, r, lane);

            float s0 = sq4v(cur.v0), s1 = sq4v(cur.v1);
            float s2 = sq4v(cur.v2), s3 = sq4v(cur.v3);
            float s4 = sq4v(cur.v4), s5 = sq4v(cur.v5);
            float s6 = sq4v(cur.v6), s7 = sq4v(cur.v7);
            #pragma unroll
            for (int m = 1; m <= 32; m <<= 1) {
                s0 += __shfl_xor(s0, m, 64);
                s1 += __shfl_xor(s1, m, 64);
                s2 += __shfl_xor(s2, m, 64);
                s3 += __shfl_xor(s3, m, 64);
                s4 += __shfl_xor(s4, m, 64);
                s5 += __shfl_xor(s5, m, 64);
                s6 += __shfl_xor(s6, m, 64);
                s7 += __shfl_xor(s7, m, 64);
            }

            if (lane == 0) {
                const float n[8] = {sqrtf(s0), sqrtf(s1), sqrtf(s2), sqrtf(s3),
                                    sqrtf(s4), sqrtf(s5), sqrtf(s6), sqrtf(s7)};
                const int b[8] = {w0.x, w0.y, w0.z, w0.w, w1.x, w1.y, w1.z, w1.w};
                int seg = b[0];
                float rs = n[0], rc = 1.0f;
                #pragma unroll
                for (int k = 1; k < 8; ++k) {
                    if (b[k] == seg) { rs += n[k]; rc += 1.0f; }
                    else {
                        atomicAdd(&sums[seg], rs);
                        atomicAdd(&cnts[seg], rc);
                        seg = b[k]; rs = n[k]; rc = 1.0f;
                    }
                }
                atomicAdd(&sums[seg], rs);
                atomicAdd(&cnts[seg], rc);
            }

            if (!more) break;
            cur = nxt; w0 = nw0; w1 = nw1; r = rn;
        }
    }
    if (waveId == 0) {
        for (int t = Nq; t < N; ++t) {
            const f4 v = ((const f4*)(x + (size_t)t * D))[lane];
            ((f4*)(out + (size_t)t * D))[lane] = v;
            float s = sq4v(v);
            #pragma unroll
            for (int m = 32; m; m >>= 1) s += __shfl_xor(s, m, 64);
            if (lane == 0) {
                atomicAdd(&sums[batch[t]], sqrtf(s));
                atomicAdd(&cnts[batch[t]], 1.0f);
            }
        }
    }
}

// ---------------------------------------------------------------------------
// finalize: per_graph = sum/count; mask i < bmax; mean / (bmax + 1).
// ---------------------------------------------------------------------------
__global__ __launch_bounds__(1024) void activs_finalize_kernel(
        const float* __restrict__ sums, const float* __restrict__ cnts,
        const int* __restrict__ batch, int N, float* __restrict__ out_scalar) {
    __shared__ float red[16];
    const int i = threadIdx.x;
    const int lane = i & 63;
    const int w = i >> 6;

    const float bmax = (float)batch[N - 1];

    float c = cnts[i];
    float pg = (c > 0.0f) ? (sums[i] / c) : 0.0f;
    float val = (((float)i) < bmax) ? pg : 0.0f;

    #pragma unroll
    for (int m = 32; m; m >>= 1) val += __shfl_xor(val, m, 64);
    if (lane == 0) red[w] = val;
    __syncthreads();

    if (w == 0) {
        float v = (lane < 16) ? red[lane] : 0.0f;
        #pragma unroll
        for (int m = 8; m; m >>= 1) v += __shfl_xor(v, m, 64);
        if (lane == 0) out_scalar[0] = v / (bmax + 1.0f);
    }
}

// ---------------------------------------------------------------------------
extern "C" void kernel_launch(void* const* d_in, const int* in_sizes, int n_in,
                              void* d_out, int out_size, void* d_ws, size_t ws_size,
                              hipStream_t stream) {
    const float* x = (const float*)d_in[0];
    const int* batch = (const int*)d_in[1];
    float* out = (float*)d_out;

    const int N = in_sizes[1];                 // 1,000,000 rows (D = 256)

    const size_t need_norm = ((size_t)N + 2 * NUM_GRAPHS) * sizeof(float);

    if (ws_size >= need_norm) {
        float* norms = (float*)d_ws;           // [N]
        float* sums = norms + N;               // [1024]
        float* cnts = sums + NUM_GRAPHS;       // [1024]

        hipLaunchKernelGGL(activs_init_kernel, dim3(4), dim3(256), 0, stream, sums, cnts);
        // TLP re-probe under NT: 2048 blocks (vs R13's 512).
        hipLaunchKernelGGL(activs_stream_kernel, dim3(2048), dim3(256), 0, stream,
                           x, out, norms, N);
        hipLaunchKernelGGL(activs_segred_kernel, dim3((N + 1023) / 1024), dim3(256),
                           0, stream, norms, batch, sums, cnts, N);
        hipLaunchKernelGGL(activs_finalize_kernel, dim3(1), dim3(1024), 0, stream,
                           sums, cnts, batch, N, out + (size_t)N * D);
    } else {
        float* sums = (float*)d_ws;            // [1024]
        float* cnts = sums + NUM_GRAPHS;       // [1024]

        hipLaunchKernelGGL(activs_init_kernel, dim3(4), dim3(256), 0, stream, sums, cnts);
        hipLaunchKernelGGL(activs_fused_kernel, dim3(2048), dim3(256), 0, stream,
                           x, batch, out, sums, cnts, N);
        hipLaunchKernelGGL(activs_finalize_kernel, dim3(1), dim3(1024), 0, stream,
                           sums, cnts, batch, N, out + (size_t)N * D);
    }
}